// Round 2
// baseline (550.104 us; speedup 1.0000x reference)
//
#include <hip/hip_runtime.h>
#include <math.h>

#define N_NODES   50000
#define N_EDGES   800000
#define IN_DIM    128
#define HID       64
#define OUT_DIM   128
#define N_GRAPHS  256
#define MAX_DEG   64      // ELL row stride; P(indeg>64) for Binomial(800k,1/50k) ~ 0

// ---------------- preprocessing ----------------

__global__ void k_hist(const int* __restrict__ dst, int* __restrict__ deg) {
    int e = blockIdx.x * blockDim.x + threadIdx.x;
    if (e < N_EDGES) atomicAdd(&deg[dst[e]], 1);
}

__global__ void k_dinv(const int* __restrict__ deg, float* __restrict__ dinv) {
    int n = blockIdx.x * blockDim.x + threadIdx.x;
    if (n < N_NODES) dinv[n] = rsqrtf((float)(deg[n] + 1));  // +1 self-loop; deg>=1 always
}

__global__ void k_fill(const int* __restrict__ src, const int* __restrict__ dst,
                       int* __restrict__ cursor, int* __restrict__ col) {
    int e = blockIdx.x * blockDim.x + threadIdx.x;
    if (e < N_EDGES) {
        int d = dst[e];
        int pos = atomicAdd(&cursor[d], 1);
        if (pos < MAX_DEG) col[d * MAX_DEG + pos] = src[e];
    }
}

// ---------------- dense GEMM: T[n][f] = (scale? dinv[n] : 1) * sum_k X[n][k] W[k][f] ----------------

template <int K>
__global__ __launch_bounds__(256) void k_gemm(const float* __restrict__ X,
                                              const float* __restrict__ W,
                                              const float* __restrict__ dinv,
                                              float* __restrict__ T, int scale) {
    __shared__ float Wl[K * HID];
    __shared__ float Xl[4 * K];
    int tid = threadIdx.x;
    for (int i = tid; i < K * HID; i += 256) Wl[i] = W[i];
    for (int i = tid; i < 4 * K; i += 256) Xl[i] = X[(size_t)blockIdx.x * 4 * K + i];
    __syncthreads();
    int f = tid & 63;
    int local = tid >> 6;              // 0..3 -> row within block
    int n = blockIdx.x * 4 + local;    // 50000 % 4 == 0, no tail
    float acc = 0.f;
#pragma unroll 8
    for (int k = 0; k < K; k++) acc += Xl[local * K + k] * Wl[k * HID + f];
    if (scale) acc *= dinv[n];
    T[(size_t)n * HID + f] = acc;
}

// ---------------- aggregation: one wave per dst node, lane = feature ----------------
// mode 0: OUT = dinv * gelu_tanh( dinv*(sum_in T[s] + T[d]) + b )   (layers 1,2; OUT pre-scaled for next layer)
// mode 1: OUT = dinv * (sum_in T[s] + T[d])                          (layer 3, pre-GEMM3 aggregate)

__global__ __launch_bounds__(256) void k_agg(const float* __restrict__ T,
                                             const int* __restrict__ col,
                                             const int* __restrict__ indeg,
                                             const float* __restrict__ dinv,
                                             const float* __restrict__ b,
                                             float* __restrict__ OUT, int mode) {
    int lane = threadIdx.x & 63;
    int d = (blockIdx.x * blockDim.x + threadIdx.x) >> 6;  // node id; 50000 waves exactly
    if (d >= N_NODES) return;
    int deg = indeg[d];
    if (deg > MAX_DEG) deg = MAX_DEG;
    int myc = (lane < deg) ? col[d * MAX_DEG + lane] : 0;
    float acc = T[(size_t)d * HID + lane];  // self-loop term
#pragma unroll 4
    for (int i = 0; i < deg; i++) {
        int s = __shfl(myc, i, 64);
        acc += T[(size_t)s * HID + lane];
    }
    float dv = dinv[d];
    float v = acc * dv;
    if (mode == 0) {
        v += b[lane];
        float u = 0.7978845608028654f * (v + 0.044715f * v * v * v);
        v = 0.5f * v * (1.0f + tanhf(u));
        v *= dv;  // pre-scale for next layer's (dinv ⊙ h) @ W
    }
    OUT[(size_t)d * HID + lane] = v;
}

// ---------------- pooling + final tiny GEMM ----------------

__global__ __launch_bounds__(256) void k_pool(const float* __restrict__ A,
                                              const int* __restrict__ batch,
                                              float* __restrict__ pool,
                                              int* __restrict__ cnt) {
    int lane = threadIdx.x & 63;
    int node = (blockIdx.x * blockDim.x + threadIdx.x) >> 6;
    if (node >= N_NODES) return;
    int g = batch[node];
    atomicAdd(&pool[g * HID + lane], A[(size_t)node * HID + lane]);
    if (lane == 0) atomicAdd(&cnt[g], 1);
}

__global__ __launch_bounds__(128) void k_out(const float* __restrict__ pool,
                                             const int* __restrict__ cnt,
                                             const float* __restrict__ W3,
                                             const float* __restrict__ b3,
                                             float* __restrict__ out) {
    int o = threadIdx.x;   // 0..127
    int g = blockIdx.x;    // 0..255
    float inv = 1.0f / fmaxf((float)cnt[g], 1.0f);
    float acc = 0.f;
#pragma unroll 8
    for (int k = 0; k < HID; k++) acc += pool[g * HID + k] * W3[k * OUT_DIM + o];
    out[g * OUT_DIM + o] = acc * inv + b3[o];
}

// ---------------- launch ----------------

extern "C" void kernel_launch(void* const* d_in, const int* in_sizes, int n_in,
                              void* d_out, int out_size, void* d_ws, size_t ws_size,
                              hipStream_t stream) {
    const float* x     = (const float*)d_in[0];
    const int*   ei    = (const int*)d_in[1];   // [2, E] row-major: row0=src, row1=dst
    const int*   batch = (const int*)d_in[2];
    const float* W1    = (const float*)d_in[4];
    const float* b1    = (const float*)d_in[5];
    const float* W2    = (const float*)d_in[6];
    const float* b2    = (const float*)d_in[7];
    const float* W3    = (const float*)d_in[8];
    const float* b3    = (const float*)d_in[9];
    float* out = (float*)d_out;

    const int* esrc = ei;
    const int* edst = ei + N_EDGES;

    // workspace layout (element offsets; zeroed region first, one contiguous memset)
    int*   deg    = (int*)d_ws;                 // 50000  (zero)
    int*   cursor = deg + N_NODES;              // 50000  (zero)
    int*   cnt    = cursor + N_NODES;           // 256    (zero)
    float* pool   = (float*)(cnt + N_GRAPHS);   // 16384  (zero)
    float* dinv   = pool + N_GRAPHS * HID;      // 50000
    int*   col    = (int*)(dinv + N_NODES);     // 50000*64 = 3.2M
    float* t      = (float*)(col + N_NODES * MAX_DEG);  // 3.2M
    float* p      = t + (size_t)N_NODES * HID;          // 3.2M

    size_t zero_bytes = (size_t)(2 * N_NODES + N_GRAPHS + N_GRAPHS * HID) * 4;
    hipMemsetAsync(d_ws, 0, zero_bytes, stream);

    const int EB = (N_EDGES + 255) / 256;   // 3125
    const int NB = N_NODES / 4;             // 12500 (4 waves/block, 1 node/wave)

    k_hist<<<EB, 256, 0, stream>>>(edst, deg);
    k_dinv<<<(N_NODES + 255) / 256, 256, 0, stream>>>(deg, dinv);
    k_fill<<<EB, 256, 0, stream>>>(esrc, edst, cursor, col);

    // layer 1: t = dinv ⊙ (x @ W1);  p = dinv ⊙ gelu(dinv*(Σ t) + b1)
    k_gemm<IN_DIM><<<NB, 256, 0, stream>>>(x, W1, dinv, t, 1);
    k_agg<<<NB, 256, 0, stream>>>(t, col, deg, dinv, b1, p, 0);

    // layer 2: t = p @ W2
    k_gemm<HID><<<NB, 256, 0, stream>>>(p, W2, dinv, t, 0);
    k_agg<<<NB, 256, 0, stream>>>(t, col, deg, dinv, b2, p, 0);

    // layer 3 aggregate (width 64, pre-GEMM): t = dinv*(Σ p + p_self)
    k_agg<<<NB, 256, 0, stream>>>(p, col, deg, dinv, b3, t, 1);

    // mean-pool then tiny GEMM 256x64 @ 64x128 + b3
    k_pool<<<NB, 256, 0, stream>>>(t, batch, pool, cnt);
    k_out<<<N_GRAPHS, 128, 0, stream>>>(pool, cnt, W3, b3, out);
}

// Round 3
// 441.906 us; speedup vs baseline: 1.2448x; 1.2448x over previous
//
#include <hip/hip_runtime.h>
#include <math.h>

#define N_NODES   50000
#define N_EDGES   800000
#define IN_DIM    128
#define HID       64
#define OUT_DIM   128
#define N_GRAPHS  256
#define MAX_DEG   64      // ELL row stride; P(indeg>64) for Binomial(800k,1/50k) ~ 0

// ---------------- preprocessing ----------------

__global__ void k_hist(const int* __restrict__ dst, int* __restrict__ deg) {
    int e = blockIdx.x * blockDim.x + threadIdx.x;
    if (e < N_EDGES) atomicAdd(&deg[dst[e]], 1);
}

__global__ void k_dinv(const int* __restrict__ deg, float* __restrict__ dinv) {
    int n = blockIdx.x * blockDim.x + threadIdx.x;
    if (n < N_NODES) dinv[n] = rsqrtf((float)(deg[n] + 1));  // +1 self-loop; deg>=1 always
}

__global__ void k_fill(const int* __restrict__ src, const int* __restrict__ dst,
                       int* __restrict__ cursor, int* __restrict__ col) {
    int e = blockIdx.x * blockDim.x + threadIdx.x;
    if (e < N_EDGES) {
        int d = dst[e];
        int pos = atomicAdd(&cursor[d], 1);
        if (pos < MAX_DEG) col[d * MAX_DEG + pos] = src[e];
    }
}

// ---------------- dense GEMM: T[n][f] = (scale? dinv[n] : 1) * sum_k X[n][k] W[k][f] ----------------

template <int K>
__global__ __launch_bounds__(256) void k_gemm(const float* __restrict__ X,
                                              const float* __restrict__ W,
                                              const float* __restrict__ dinv,
                                              float* __restrict__ T, int scale) {
    __shared__ float Wl[K * HID];
    __shared__ float Xl[4 * K];
    int tid = threadIdx.x;
    for (int i = tid; i < K * HID; i += 256) Wl[i] = W[i];
    for (int i = tid; i < 4 * K; i += 256) Xl[i] = X[(size_t)blockIdx.x * 4 * K + i];
    __syncthreads();
    int f = tid & 63;
    int local = tid >> 6;              // 0..3 -> row within block
    int n = blockIdx.x * 4 + local;    // 50000 % 4 == 0, no tail
    float acc = 0.f;
#pragma unroll 8
    for (int k = 0; k < K; k++) acc += Xl[local * K + k] * Wl[k * HID + f];
    if (scale) acc *= dinv[n];
    T[(size_t)n * HID + f] = acc;
}

// ---------------- aggregation: one wave per dst node, lane = feature ----------------
// mode 0: OUT = dinv * gelu_tanh( dinv*(sum_in T[s] + T[d]) + b )   (layers 1,2; OUT pre-scaled)
// mode 1: OUT = dinv * (sum_in T[s] + T[d])                          (layer 3, pre-GEMM3 aggregate)

__global__ __launch_bounds__(256) void k_agg(const float* __restrict__ T,
                                             const int* __restrict__ col,
                                             const int* __restrict__ indeg,
                                             const float* __restrict__ dinv,
                                             const float* __restrict__ b,
                                             float* __restrict__ OUT, int mode) {
    int lane = threadIdx.x & 63;
    int d = (blockIdx.x * blockDim.x + threadIdx.x) >> 6;  // node id; 50000 waves exactly
    if (d >= N_NODES) return;
    int deg = indeg[d];
    if (deg > MAX_DEG) deg = MAX_DEG;
    int myc = (lane < deg) ? col[d * MAX_DEG + lane] : 0;
    float acc = T[(size_t)d * HID + lane];  // self-loop term
#pragma unroll 4
    for (int i = 0; i < deg; i++) {
        int s = __shfl(myc, i, 64);
        acc += T[(size_t)s * HID + lane];
    }
    float dv = dinv[d];
    float v = acc * dv;
    if (mode == 0) {
        v += b[lane];
        float u = 0.7978845608028654f * (v + 0.044715f * v * v * v);
        v = 0.5f * v * (1.0f + tanhf(u));
        v *= dv;  // pre-scale for next layer's (dinv ⊙ h) @ W
    }
    OUT[(size_t)d * HID + lane] = v;
}

// ---------------- fused segmented mean-pool + final GEMM (batch is SORTED) ----------------
// out[g][o] = (pooled[g] @ W3)[o] * inv + b3[o]*cnt*inv,  inv = 1/max(cnt,1)

__global__ __launch_bounds__(256) void k_pool_out(const float* __restrict__ A,
                                                  const int* __restrict__ batch,
                                                  const float* __restrict__ W3,
                                                  const float* __restrict__ b3,
                                                  float* __restrict__ out) {
    int g = blockIdx.x;
    // lower_bound(batch, g) and lower_bound(batch, g+1) — all threads redundantly (16 iters)
    int lo = 0, hi = N_NODES;
    while (lo < hi) { int m = (lo + hi) >> 1; if (batch[m] < g) lo = m + 1; else hi = m; }
    int lo2 = lo, hi2 = N_NODES;
    while (lo2 < hi2) { int m = (lo2 + hi2) >> 1; if (batch[m] < g + 1) lo2 = m + 1; else hi2 = m; }
    int start = lo, end = lo2;

    int lane = threadIdx.x & 63;
    int wave = threadIdx.x >> 6;   // 0..3
    float acc = 0.f;
    for (int n = start + wave; n < end; n += 4)
        acc += A[(size_t)n * HID + lane];

    __shared__ float part[4][HID];
    __shared__ float pooled[HID];
    part[wave][lane] = acc;
    __syncthreads();
    if (threadIdx.x < HID)
        pooled[threadIdx.x] = part[0][threadIdx.x] + part[1][threadIdx.x] +
                              part[2][threadIdx.x] + part[3][threadIdx.x];
    __syncthreads();

    if (threadIdx.x < OUT_DIM) {
        float cntf = (float)(end - start);
        float inv = 1.0f / fmaxf(cntf, 1.0f);
        float s = 0.f;
#pragma unroll
        for (int k = 0; k < HID; k++) s += pooled[k] * W3[k * OUT_DIM + threadIdx.x];
        out[g * OUT_DIM + threadIdx.x] = (s + cntf * b3[threadIdx.x]) * inv;
    }
}

// ---------------- launch ----------------

extern "C" void kernel_launch(void* const* d_in, const int* in_sizes, int n_in,
                              void* d_out, int out_size, void* d_ws, size_t ws_size,
                              hipStream_t stream) {
    const float* x     = (const float*)d_in[0];
    const int*   ei    = (const int*)d_in[1];   // [2, E] row-major: row0=src, row1=dst
    const int*   batch = (const int*)d_in[2];
    const float* W1    = (const float*)d_in[4];
    const float* b1    = (const float*)d_in[5];
    const float* W2    = (const float*)d_in[6];
    const float* b2    = (const float*)d_in[7];
    const float* W3    = (const float*)d_in[8];
    const float* b3    = (const float*)d_in[9];
    float* out = (float*)d_out;

    const int* esrc = ei;
    const int* edst = ei + N_EDGES;

    // workspace layout (element offsets; zeroed region first, one contiguous memset)
    int*   deg    = (int*)d_ws;                 // 50000  (zero)
    int*   cursor = deg + N_NODES;              // 50000  (zero)
    float* dinv   = (float*)(cursor + N_NODES); // 50000
    int*   col    = (int*)(dinv + N_NODES);     // 50000*64 = 3.2M
    float* t      = (float*)(col + N_NODES * MAX_DEG);  // 3.2M
    float* p      = t + (size_t)N_NODES * HID;          // 3.2M

    hipMemsetAsync(d_ws, 0, (size_t)(2 * N_NODES) * 4, stream);

    const int EB = (N_EDGES + 255) / 256;   // 3125
    const int NB = N_NODES / 4;             // 12500 (4 waves/block, 1 node/wave)

    k_hist<<<EB, 256, 0, stream>>>(edst, deg);
    k_dinv<<<(N_NODES + 255) / 256, 256, 0, stream>>>(deg, dinv);
    k_fill<<<EB, 256, 0, stream>>>(esrc, edst, cursor, col);

    // layer 1: t = dinv ⊙ (x @ W1);  p = dinv ⊙ gelu(dinv*(Σ t) + b1)
    k_gemm<IN_DIM><<<NB, 256, 0, stream>>>(x, W1, dinv, t, 1);
    k_agg<<<NB, 256, 0, stream>>>(t, col, deg, dinv, b1, p, 0);

    // layer 2: t = p @ W2
    k_gemm<HID><<<NB, 256, 0, stream>>>(p, W2, dinv, t, 0);
    k_agg<<<NB, 256, 0, stream>>>(t, col, deg, dinv, b2, p, 0);

    // layer 3 aggregate (width 64, pre-GEMM): t = dinv*(Σ p + p_self)
    k_agg<<<NB, 256, 0, stream>>>(p, col, deg, dinv, b3, t, 1);

    // fused mean-pool + 64->128 GEMM (batch sorted -> segmented reduce, no atomics)
    k_pool_out<<<N_GRAPHS, 256, 0, stream>>>(t, batch, W3, b3, out);
}

// Round 4
// 433.047 us; speedup vs baseline: 1.2703x; 1.0205x over previous
//
#include <hip/hip_runtime.h>
#include <hip/hip_fp16.h>
#include <math.h>

#define N_NODES   50000
#define N_EDGES   800000
#define IN_DIM    128
#define HID       64
#define OUT_DIM   128
#define N_GRAPHS  256
#define MAX_DEG   64      // ELL row stride; P(indeg>64) for Binomial(800k,1/50k) ~ 0

__device__ __forceinline__ float toF(float v) { return v; }
__device__ __forceinline__ float toF(__half v) { return __half2float(v); }

// ---------------- preprocessing ----------------

__global__ void k_hist(const int* __restrict__ dst, int* __restrict__ deg) {
    int e = blockIdx.x * blockDim.x + threadIdx.x;
    if (e < N_EDGES) atomicAdd(&deg[dst[e]], 1);
}

__global__ void k_dinv(const int* __restrict__ deg, float* __restrict__ dinv) {
    int n = blockIdx.x * blockDim.x + threadIdx.x;
    if (n < N_NODES) dinv[n] = rsqrtf((float)(deg[n] + 1));  // +1 self-loop
}

__global__ void k_fill(const int* __restrict__ src, const int* __restrict__ dst,
                       int* __restrict__ cursor, int* __restrict__ col) {
    int e = blockIdx.x * blockDim.x + threadIdx.x;
    if (e < N_EDGES) {
        int d = dst[e];
        int pos = atomicAdd(&cursor[d], 1);
        if (pos < MAX_DEG) col[d * MAX_DEG + pos] = src[e];
    }
}

// ---------------- dense GEMM: T[n][f] = (scale? dinv[n] : 1) * sum_k X[n][k] W[k][f] ----------------
// compute fp32, output fp16

template <int K, typename XT>
__global__ __launch_bounds__(256) void k_gemm(const XT* __restrict__ X,
                                              const float* __restrict__ W,
                                              const float* __restrict__ dinv,
                                              __half* __restrict__ T, int scale) {
    __shared__ float Wl[K * HID];
    __shared__ float Xl[4 * K];
    int tid = threadIdx.x;
    for (int i = tid; i < K * HID; i += 256) Wl[i] = W[i];
    for (int i = tid; i < 4 * K; i += 256) Xl[i] = toF(X[(size_t)blockIdx.x * 4 * K + i]);
    __syncthreads();
    int f = tid & 63;
    int local = tid >> 6;              // 0..3 -> row within block
    int n = blockIdx.x * 4 + local;    // 50000 % 4 == 0, no tail
    float acc = 0.f;
#pragma unroll 8
    for (int k = 0; k < K; k++) acc += Xl[local * K + k] * Wl[k * HID + f];
    if (scale) acc *= dinv[n];
    T[(size_t)n * HID + f] = __float2half(acc);
}

// ---------------- aggregation: one wave per dst node, lane = feature ----------------
// mode 0: OUT = dinv * gelu_tanh( dinv*(sum_in T[s] + T[d]) + b )   (layers 1,2; OUT pre-scaled)
// mode 1: OUT = dinv * (sum_in T[s] + T[d])                          (layer 3, pre-GEMM3 aggregate)

__global__ __launch_bounds__(256) void k_agg(const __half* __restrict__ T,
                                             const int* __restrict__ col,
                                             const int* __restrict__ indeg,
                                             const float* __restrict__ dinv,
                                             const float* __restrict__ b,
                                             __half* __restrict__ OUT, int mode) {
    int lane = threadIdx.x & 63;
    int d = (blockIdx.x * blockDim.x + threadIdx.x) >> 6;  // node id; 50000 waves exactly
    if (d >= N_NODES) return;
    int deg = indeg[d];
    if (deg > MAX_DEG) deg = MAX_DEG;
    int myc = (lane < deg) ? col[d * MAX_DEG + lane] : 0;
    float acc = __half2float(T[(size_t)d * HID + lane]);  // self-loop term
#pragma unroll 4
    for (int i = 0; i < deg; i++) {
        int s = __shfl(myc, i, 64);
        acc += __half2float(T[(size_t)s * HID + lane]);
    }
    float dv = dinv[d];
    float v = acc * dv;
    if (mode == 0) {
        v += b[lane];
        float u = 0.7978845608028654f * (v + 0.044715f * v * v * v);
        v = 0.5f * v * (1.0f + tanhf(u));
        v *= dv;  // pre-scale for next layer's (dinv ⊙ h) @ W
    }
    OUT[(size_t)d * HID + lane] = __float2half(v);
}

// ---------------- fused segmented mean-pool + final GEMM (batch is SORTED) ----------------

__global__ __launch_bounds__(256) void k_pool_out(const __half* __restrict__ A,
                                                  const int* __restrict__ batch,
                                                  const float* __restrict__ W3,
                                                  const float* __restrict__ b3,
                                                  float* __restrict__ out) {
    int g = blockIdx.x;
    int lo = 0, hi = N_NODES;
    while (lo < hi) { int m = (lo + hi) >> 1; if (batch[m] < g) lo = m + 1; else hi = m; }
    int lo2 = lo, hi2 = N_NODES;
    while (lo2 < hi2) { int m = (lo2 + hi2) >> 1; if (batch[m] < g + 1) lo2 = m + 1; else hi2 = m; }
    int start = lo, end = lo2;

    int lane = threadIdx.x & 63;
    int wave = threadIdx.x >> 6;   // 0..3
    float acc = 0.f;
    for (int n = start + wave; n < end; n += 4)
        acc += __half2float(A[(size_t)n * HID + lane]);

    __shared__ float part[4][HID];
    __shared__ float pooled[HID];
    part[wave][lane] = acc;
    __syncthreads();
    if (threadIdx.x < HID)
        pooled[threadIdx.x] = part[0][threadIdx.x] + part[1][threadIdx.x] +
                              part[2][threadIdx.x] + part[3][threadIdx.x];
    __syncthreads();

    if (threadIdx.x < OUT_DIM) {
        float cntf = (float)(end - start);
        float inv = 1.0f / fmaxf(cntf, 1.0f);
        float s = 0.f;
#pragma unroll
        for (int k = 0; k < HID; k++) s += pooled[k] * W3[k * OUT_DIM + threadIdx.x];
        out[g * OUT_DIM + threadIdx.x] = (s + cntf * b3[threadIdx.x]) * inv;
    }
}

// ---------------- launch ----------------

extern "C" void kernel_launch(void* const* d_in, const int* in_sizes, int n_in,
                              void* d_out, int out_size, void* d_ws, size_t ws_size,
                              hipStream_t stream) {
    const float* x     = (const float*)d_in[0];
    const int*   ei    = (const int*)d_in[1];   // [2, E]: row0=src, row1=dst
    const int*   batch = (const int*)d_in[2];
    const float* W1    = (const float*)d_in[4];
    const float* b1    = (const float*)d_in[5];
    const float* W2    = (const float*)d_in[6];
    const float* b2    = (const float*)d_in[7];
    const float* W3    = (const float*)d_in[8];
    const float* b3    = (const float*)d_in[9];
    float* out = (float*)d_out;

    const int* esrc = ei;
    const int* edst = ei + N_EDGES;

    // workspace layout
    int*    deg    = (int*)d_ws;                 // 50000  (zero)
    int*    cursor = deg + N_NODES;              // 50000  (zero)
    float*  dinv   = (float*)(cursor + N_NODES); // 50000
    int*    col    = (int*)(dinv + N_NODES);     // 3.2M ints
    __half* t      = (__half*)(col + N_NODES * MAX_DEG);  // 3.2M halves (6.4 MB)
    __half* p      = t + (size_t)N_NODES * HID;           // 3.2M halves

    hipMemsetAsync(d_ws, 0, (size_t)(2 * N_NODES) * 4, stream);

    const int EB = (N_EDGES + 255) / 256;   // 3125
    const int NB = N_NODES / 4;             // 12500

    k_hist<<<EB, 256, 0, stream>>>(edst, deg);
    k_dinv<<<(N_NODES + 255) / 256, 256, 0, stream>>>(deg, dinv);
    k_fill<<<EB, 256, 0, stream>>>(esrc, edst, cursor, col);

    // layer 1: t = dinv ⊙ (x @ W1);  p = dinv ⊙ gelu(dinv*(Σ t) + b1)
    k_gemm<IN_DIM, float><<<NB, 256, 0, stream>>>(x, W1, dinv, t, 1);
    k_agg<<<NB, 256, 0, stream>>>(t, col, deg, dinv, b1, p, 0);

    // layer 2
    k_gemm<HID, __half><<<NB, 256, 0, stream>>>(p, W2, dinv, t, 0);
    k_agg<<<NB, 256, 0, stream>>>(t, col, deg, dinv, b2, p, 0);

    // layer 3 aggregate (width 64, pre-GEMM)
    k_agg<<<NB, 256, 0, stream>>>(p, col, deg, dinv, b3, t, 1);

    // fused mean-pool + 64->128 GEMM
    k_pool_out<<<N_GRAPHS, 256, 0, stream>>>(t, batch, W3, b3, out);
}

// Round 5
// 254.813 us; speedup vs baseline: 2.1589x; 1.6995x over previous
//
#include <hip/hip_runtime.h>
#include <hip/hip_fp16.h>
#include <math.h>

#define N_NODES   50000
#define N_EDGES   800000
#define IN_DIM    128
#define HID       64
#define OUT_DIM   128
#define N_GRAPHS  256
#define MAX_DEG   64      // ELL row stride; P(indeg>64) for Binomial(800k,1/50k) ~ 0

typedef _Float16 half8 __attribute__((ext_vector_type(8)));
typedef float floatx4 __attribute__((ext_vector_type(4)));

// ---------------- preprocessing ----------------

// merged histogram + ELL fill: deg doubles as cursor; final deg = in-degree
__global__ void k_build(const int* __restrict__ src, const int* __restrict__ dst,
                        int* __restrict__ deg, int* __restrict__ col) {
    int e = blockIdx.x * blockDim.x + threadIdx.x;
    if (e < N_EDGES) {
        int d = dst[e];
        int pos = atomicAdd(&deg[d], 1);
        if (pos < MAX_DEG) col[d * MAX_DEG + pos] = src[e];
    }
}

__global__ void k_dinv(const int* __restrict__ deg, float* __restrict__ dinv) {
    int n = blockIdx.x * blockDim.x + threadIdx.x;
    if (n < N_NODES) dinv[n] = rsqrtf((float)(deg[n] + 1));  // +1 self-loop
}

// x -> fp16, pre-scaled by dinv[row]  (t = dinv ⊙ (x@W1) == (dinv⊙x)@W1)
__global__ void k_xcvt(const float* __restrict__ x, const float* __restrict__ dinv,
                       __half* __restrict__ xh) {
    int idx = blockIdx.x * blockDim.x + threadIdx.x;   // float4 index
    if (idx < N_NODES * IN_DIM / 4) {
        int row = idx >> 5;  // /32 (=128/4)
        float dv = dinv[row];
        float4 v = ((const float4*)x)[idx];
        __half2 h0 = __floats2half2_rn(v.x * dv, v.y * dv);
        __half2 h1 = __floats2half2_rn(v.z * dv, v.w * dv);
        ((__half2*)xh)[2 * idx]     = h0;
        ((__half2*)xh)[2 * idx + 1] = h1;
    }
}

// pack W [K][64] fp32 -> Wt: Wt[(g*64+n)*8 + i] = W[8g+i][n]   (B-fragment-friendly)
__global__ void k_pack(const float* __restrict__ W, __half* __restrict__ Wt, int K) {
    int idx = blockIdx.x * blockDim.x + threadIdx.x;   // g*64+n
    int total = (K / 8) * 64;
    if (idx < total) {
        int g = idx >> 6, n = idx & 63;
#pragma unroll
        for (int i = 0; i < 8; i++)
            Wt[idx * 8 + i] = __float2half(W[(8 * g + i) * 64 + n]);
    }
}

// ---------------- MFMA GEMM: C[M][64] = A[M][K] @ W[K][64], fp16 in, fp32 acc, fp16 out ----------------
// block = 256 (4 waves), tile 64 rows x 64 cols; wave = 16-row strip, 4 N-tiles of 16

template <int K>
__global__ __launch_bounds__(256) void k_mfma(const __half* __restrict__ A,
                                              const __half* __restrict__ Bp,
                                              __half* __restrict__ C) {
    constexpr int S = K / 32;          // K-steps
    int wv   = threadIdx.x >> 6;
    int lane = threadIdx.x & 63;
    int quad = lane >> 4, l15 = lane & 15;
    int row0 = blockIdx.x * 64 + wv * 16;
    if (row0 >= N_NODES) return;       // tail: 50000 % 16 == 0, strips all-valid or all-invalid

    // B fragments: B[k=32s+quad*8+i][n=16j+l15] -> packed at ((4s+quad)*64 + n)*8
    half8 bf[S][4];
#pragma unroll
    for (int s = 0; s < S; s++)
#pragma unroll
        for (int j = 0; j < 4; j++)
            bf[s][j] = *(const half8*)(Bp + ((size_t)((4 * s + quad) * 64 + 16 * j + l15)) * 8);

    floatx4 acc[4];
#pragma unroll
    for (int j = 0; j < 4; j++) acc[j] = 0.f;

    int arow = row0 + l15;
#pragma unroll
    for (int s = 0; s < S; s++) {
        half8 af = *(const half8*)(A + (size_t)arow * K + 32 * s + quad * 8);
#pragma unroll
        for (int j = 0; j < 4; j++)
            acc[j] = __builtin_amdgcn_mfma_f32_16x16x32_f16(af, bf[s][j], acc[j], 0, 0, 0);
    }
    // D: col = 16j + l15, row_local = quad*4 + r
#pragma unroll
    for (int j = 0; j < 4; j++)
#pragma unroll
        for (int r = 0; r < 4; r++) {
            int row = row0 + quad * 4 + r;
            C[(size_t)row * 64 + 16 * j + l15] = __float2half(acc[j][r]);
        }
}

// ---------------- aggregation: 4 dst nodes per wave, lane = (node-quad, 4-feat chunk) ----------------
// mode 0: OUT = dinv * gelu_tanh( dinv*(Σ_in T[s] + T[d]) + b )   (pre-scaled for next layer)
// mode 1: OUT = dinv * (Σ_in T[s] + T[d])

__global__ __launch_bounds__(256) void k_agg(const __half* __restrict__ T,
                                             const int* __restrict__ col,
                                             const int* __restrict__ indeg,
                                             const float* __restrict__ dinv,
                                             const float* __restrict__ b,
                                             __half* __restrict__ OUT, int mode) {
    int lane = threadIdx.x & 63;
    int wv   = threadIdx.x >> 6;
    int q = lane >> 4, t = lane & 15;
    int d = (blockIdx.x * 4 + wv) * 4 + q;       // grid = 3125 blocks -> 50000 nodes exactly
    int dg = indeg[d]; if (dg > MAX_DEG) dg = MAX_DEG;
    int m1 = max(dg, __shfl_xor(dg, 16));
    int mx = max(m1, __shfl_xor(m1, 32));        // max deg over the wave's 4 nodes

    // self term
    uint2 u = *(const uint2*)(T + (size_t)d * HID + 4 * t);
    __half2 ha = *(__half2*)&u.x, hb = *(__half2*)&u.y;
    float4 acc = make_float4(__low2float(ha), __high2float(ha), __low2float(hb), __high2float(hb));

    for (int base = 0; base < mx; base += 16) {
        int c = 0;
        if (base + t < dg) c = col[d * MAX_DEG + base + t];
        int lim = mx - base; if (lim > 16) lim = 16;
        for (int i = 0; i < lim; i++) {
            int s = __shfl(c, q * 16 + i, 64);               // 0 if that slot OOB -> safe addr
            uint2 v = *(const uint2*)(T + (size_t)s * HID + 4 * t);
            if (base + i < dg) {
                __half2 va = *(__half2*)&v.x, vb = *(__half2*)&v.y;
                acc.x += __low2float(va); acc.y += __high2float(va);
                acc.z += __low2float(vb); acc.w += __high2float(vb);
            }
        }
    }

    float dv = dinv[d];
    float o[4] = {acc.x * dv, acc.y * dv, acc.z * dv, acc.w * dv};
    if (mode == 0) {
#pragma unroll
        for (int j = 0; j < 4; j++) {
            float v = o[j] + b[4 * t + j];
            float u2 = 0.7978845608028654f * (v + 0.044715f * v * v * v);
            o[j] = 0.5f * v * (1.0f + tanhf(u2)) * dv;   // pre-scale for next layer
        }
    }
    __half2 s0 = __floats2half2_rn(o[0], o[1]);
    __half2 s1 = __floats2half2_rn(o[2], o[3]);
    uint2 st; st.x = *(unsigned*)&s0; st.y = *(unsigned*)&s1;
    *(uint2*)(OUT + (size_t)d * HID + 4 * t) = st;
}

// ---------------- fused segmented mean-pool + final GEMM (batch is SORTED) ----------------

__global__ __launch_bounds__(256) void k_pool_out(const __half* __restrict__ A,
                                                  const int* __restrict__ batch,
                                                  const float* __restrict__ W3,
                                                  const float* __restrict__ b3,
                                                  float* __restrict__ out) {
    int g = blockIdx.x;
    int lo = 0, hi = N_NODES;
    while (lo < hi) { int m = (lo + hi) >> 1; if (batch[m] < g) lo = m + 1; else hi = m; }
    int lo2 = lo, hi2 = N_NODES;
    while (lo2 < hi2) { int m = (lo2 + hi2) >> 1; if (batch[m] < g + 1) lo2 = m + 1; else hi2 = m; }
    int start = lo, end = lo2;

    int lane = threadIdx.x & 63;
    int wave = threadIdx.x >> 6;
    float acc = 0.f;
    for (int n = start + wave; n < end; n += 4)
        acc += __half2float(A[(size_t)n * HID + lane]);

    __shared__ float part[4][HID];
    __shared__ float pooled[HID];
    part[wave][lane] = acc;
    __syncthreads();
    if (threadIdx.x < HID)
        pooled[threadIdx.x] = part[0][threadIdx.x] + part[1][threadIdx.x] +
                              part[2][threadIdx.x] + part[3][threadIdx.x];
    __syncthreads();

    if (threadIdx.x < OUT_DIM) {
        float cntf = (float)(end - start);
        float inv = 1.0f / fmaxf(cntf, 1.0f);
        float s = 0.f;
#pragma unroll
        for (int k = 0; k < HID; k++) s += pooled[k] * W3[k * OUT_DIM + threadIdx.x];
        out[g * OUT_DIM + threadIdx.x] = (s + cntf * b3[threadIdx.x]) * inv;
    }
}

// ---------------- launch ----------------

extern "C" void kernel_launch(void* const* d_in, const int* in_sizes, int n_in,
                              void* d_out, int out_size, void* d_ws, size_t ws_size,
                              hipStream_t stream) {
    const float* x     = (const float*)d_in[0];
    const int*   ei    = (const int*)d_in[1];
    const int*   batch = (const int*)d_in[2];
    const float* W1    = (const float*)d_in[4];
    const float* b1    = (const float*)d_in[5];
    const float* W2    = (const float*)d_in[6];
    const float* b2    = (const float*)d_in[7];
    const float* W3    = (const float*)d_in[8];
    const float* b3    = (const float*)d_in[9];
    float* out = (float*)d_out;

    const int* esrc = ei;
    const int* edst = ei + N_EDGES;

    // workspace layout
    int*    deg  = (int*)d_ws;                           // 50000 (zeroed; doubles as cursor)
    float*  dinv = (float*)(deg + N_NODES);              // 50000
    int*    col  = (int*)(dinv + N_NODES);               // 3.2M ints (12.8 MB)
    __half* t    = (__half*)(col + (size_t)N_NODES * MAX_DEG);   // 3.2M halves
    __half* p    = t + (size_t)N_NODES * HID;                    // 3.2M halves
    __half* xh   = p + (size_t)N_NODES * HID;                    // 6.4M halves (12.8 MB)
    __half* Wt1  = xh + (size_t)N_NODES * IN_DIM;                // 8192 halves
    __half* Wt2  = Wt1 + IN_DIM * HID;                           // 4096 halves

    hipMemsetAsync(deg, 0, (size_t)N_NODES * 4, stream);

    const int EB = (N_EDGES + 255) / 256;

    k_build<<<EB, 256, 0, stream>>>(esrc, edst, deg, col);
    k_dinv<<<(N_NODES + 255) / 256, 256, 0, stream>>>(deg, dinv);
    k_xcvt<<<(N_NODES * IN_DIM / 4 + 255) / 256, 256, 0, stream>>>(x, dinv, xh);
    k_pack<<<((IN_DIM / 8) * 64 + 255) / 256, 256, 0, stream>>>(W1, Wt1, IN_DIM);
    k_pack<<<((HID / 8) * 64 + 255) / 256, 256, 0, stream>>>(W2, Wt2, HID);

    const int GB = (N_NODES + 63) / 64;   // 782 MFMA blocks
    const int AB = N_NODES / 16;          // 3125 agg blocks (16 nodes each)

    // layer 1
    k_mfma<IN_DIM><<<GB, 256, 0, stream>>>(xh, Wt1, t);
    k_agg<<<AB, 256, 0, stream>>>(t, col, deg, dinv, b1, p, 0);
    // layer 2
    k_mfma<HID><<<GB, 256, 0, stream>>>(p, Wt2, t);
    k_agg<<<AB, 256, 0, stream>>>(t, col, deg, dinv, b2, p, 0);
    // layer 3 aggregate (width 64, pre-GEMM)
    k_agg<<<AB, 256, 0, stream>>>(p, col, deg, dinv, b3, t, 1);
    // fused mean-pool + 64->128 GEMM
    k_pool_out<<<N_GRAPHS, 256, 0, stream>>>(t, batch, W3, b3, out);
}

// Round 6
// 221.148 us; speedup vs baseline: 2.4875x; 1.1522x over previous
//
#include <hip/hip_runtime.h>
#include <hip/hip_fp16.h>
#include <math.h>

#define N_NODES   50000
#define N_EDGES   800000
#define IN_DIM    128
#define HID       64
#define OUT_DIM   128
#define N_GRAPHS  256
#define MAX_DEG   64      // ELL row stride; P(indeg>64) for Binomial(800k,1/50k) ~ 0
#define PARTS     8       // XCD count; blockIdx%8 -> XCD round-robin heuristic
#define PSIZE     (N_NODES / PARTS)   // 6250 nodes per partition
#define EPB       4096    // edges per chunk (256 thr x 16)

typedef _Float16 half8 __attribute__((ext_vector_type(8)));
typedef float floatx4 __attribute__((ext_vector_type(4)));

// ---------------- preprocessing ----------------

// XCD-partitioned histogram + ELL fill: block (p = blockIdx%8) commits only dst in its
// 6250-node slice -> col/deg writes stay in one XCD's L2 (write-churn fix, R5 postmortem).
__global__ __launch_bounds__(256) void k_build(const int* __restrict__ src,
                                               const int* __restrict__ dst,
                                               int* __restrict__ deg, int* __restrict__ col) {
    int p     = blockIdx.x & (PARTS - 1);
    int chunk = blockIdx.x >> 3;
    int base  = chunk * EPB;
    int lo = p * PSIZE, hi = lo + PSIZE;
#pragma unroll
    for (int j = 0; j < EPB / 256; j++) {
        int e = base + j * 256 + threadIdx.x;
        if (e < N_EDGES) {
            int d = dst[e];
            if (d >= lo && d < hi) {
                int pos = atomicAdd(&deg[d], 1);
                if (pos < MAX_DEG) col[d * MAX_DEG + pos] = src[e];
            }
        }
    }
}

__global__ void k_dinv(const int* __restrict__ deg, float* __restrict__ dinv) {
    int n = blockIdx.x * blockDim.x + threadIdx.x;
    if (n < N_NODES) dinv[n] = rsqrtf((float)(deg[n] + 1));  // +1 self-loop
}

// pack W [K][64] fp32 -> Wt: Wt[(g*64+n)*8 + i] = W[8g+i][n]   (B-fragment order)
__global__ void k_pack(const float* __restrict__ W, __half* __restrict__ Wt, int K) {
    int idx = blockIdx.x * blockDim.x + threadIdx.x;   // g*64+n
    int total = (K / 8) * 64;
    if (idx < total) {
        int g = idx >> 6, n = idx & 63;
#pragma unroll
        for (int i = 0; i < 8; i++)
            Wt[idx * 8 + i] = __float2half(W[(8 * g + i) * 64 + n]);
    }
}

// ---------------- MFMA GEMM layer 1: C = (dinv ⊙ x_fp32) @ W1, cvt fused in-register ----------------

__global__ __launch_bounds__(256) void k_mfma1(const float* __restrict__ A,
                                               const float* __restrict__ dinv,
                                               const __half* __restrict__ Bp,
                                               __half* __restrict__ C) {
    constexpr int K = IN_DIM, S = K / 32;
    int wv   = threadIdx.x >> 6;
    int lane = threadIdx.x & 63;
    int quad = lane >> 4, l15 = lane & 15;
    int row0 = blockIdx.x * 64 + wv * 16;
    if (row0 >= N_NODES) return;   // 50000 % 16 == 0: strips all-valid or all-invalid

    half8 bf[S][4];
#pragma unroll
    for (int s = 0; s < S; s++)
#pragma unroll
        for (int j = 0; j < 4; j++)
            bf[s][j] = *(const half8*)(Bp + ((size_t)((4 * s + quad) * 64 + 16 * j + l15)) * 8);

    floatx4 acc[4];
#pragma unroll
    for (int j = 0; j < 4; j++) acc[j] = 0.f;

    int arow = row0 + l15;
    float dv = dinv[arow];
#pragma unroll
    for (int s = 0; s < S; s++) {
        float4 xa = *(const float4*)(A + (size_t)arow * K + 32 * s + quad * 8);
        float4 xb = *(const float4*)(A + (size_t)arow * K + 32 * s + quad * 8 + 4);
        half8 af;
        af[0] = (_Float16)(xa.x * dv); af[1] = (_Float16)(xa.y * dv);
        af[2] = (_Float16)(xa.z * dv); af[3] = (_Float16)(xa.w * dv);
        af[4] = (_Float16)(xb.x * dv); af[5] = (_Float16)(xb.y * dv);
        af[6] = (_Float16)(xb.z * dv); af[7] = (_Float16)(xb.w * dv);
#pragma unroll
        for (int j = 0; j < 4; j++)
            acc[j] = __builtin_amdgcn_mfma_f32_16x16x32_f16(af, bf[s][j], acc[j], 0, 0, 0);
    }
#pragma unroll
    for (int j = 0; j < 4; j++)
#pragma unroll
        for (int r = 0; r < 4; r++)
            C[(size_t)(row0 + quad * 4 + r) * 64 + 16 * j + l15] = __float2half(acc[j][r]);
}

// ---------------- MFMA GEMM layer 2: fp16 A ----------------

__global__ __launch_bounds__(256) void k_mfma2(const __half* __restrict__ A,
                                               const __half* __restrict__ Bp,
                                               __half* __restrict__ C) {
    constexpr int K = HID, S = K / 32;
    int wv   = threadIdx.x >> 6;
    int lane = threadIdx.x & 63;
    int quad = lane >> 4, l15 = lane & 15;
    int row0 = blockIdx.x * 64 + wv * 16;
    if (row0 >= N_NODES) return;

    half8 bf[S][4];
#pragma unroll
    for (int s = 0; s < S; s++)
#pragma unroll
        for (int j = 0; j < 4; j++)
            bf[s][j] = *(const half8*)(Bp + ((size_t)((4 * s + quad) * 64 + 16 * j + l15)) * 8);

    floatx4 acc[4];
#pragma unroll
    for (int j = 0; j < 4; j++) acc[j] = 0.f;

    int arow = row0 + l15;
#pragma unroll
    for (int s = 0; s < S; s++) {
        half8 af = *(const half8*)(A + (size_t)arow * K + 32 * s + quad * 8);
#pragma unroll
        for (int j = 0; j < 4; j++)
            acc[j] = __builtin_amdgcn_mfma_f32_16x16x32_f16(af, bf[s][j], acc[j], 0, 0, 0);
    }
#pragma unroll
    for (int j = 0; j < 4; j++)
#pragma unroll
        for (int r = 0; r < 4; r++)
            C[(size_t)(row0 + quad * 4 + r) * 64 + 16 * j + l15] = __float2half(acc[j][r]);
}

// ---------------- aggregation: 4 dst nodes/wave, 4-deep load pipeline ----------------

__device__ __forceinline__ void addv(float4& acc, uint2 v) {
    __half2 va = *(__half2*)&v.x, vb = *(__half2*)&v.y;
    acc.x += __low2float(va); acc.y += __high2float(va);
    acc.z += __low2float(vb); acc.w += __high2float(vb);
}

__global__ __launch_bounds__(256) void k_agg(const __half* __restrict__ T,
                                             const int* __restrict__ col,
                                             const int* __restrict__ indeg,
                                             const float* __restrict__ dinv,
                                             const float* __restrict__ b,
                                             __half* __restrict__ OUT, int mode) {
    int lane = threadIdx.x & 63;
    int wv   = threadIdx.x >> 6;
    int q = lane >> 4, t = lane & 15;
    int d = (blockIdx.x * 4 + wv) * 4 + q;       // 3125 blocks -> 50000 nodes exactly
    int dg = indeg[d]; if (dg > MAX_DEG) dg = MAX_DEG;
    int m1 = max(dg, __shfl_xor(dg, 16));
    int mx = max(m1, __shfl_xor(m1, 32));        // max deg over the wave's 4 nodes

    uint2 u = *(const uint2*)(T + (size_t)d * HID + 4 * t);
    float4 acc = make_float4(0.f, 0.f, 0.f, 0.f);
    addv(acc, u);                                 // self term

    for (int base = 0; base < mx; base += 16) {
        int c = (base + t < dg) ? col[d * MAX_DEG + base + t] : 0;
        int lim = mx - base; if (lim > 16) lim = 16;
        int i = 0;
        for (; i + 4 <= lim; i += 4) {
            int s0 = __shfl(c, q * 16 + i,     64);
            int s1 = __shfl(c, q * 16 + i + 1, 64);
            int s2 = __shfl(c, q * 16 + i + 2, 64);
            int s3 = __shfl(c, q * 16 + i + 3, 64);
            uint2 v0 = *(const uint2*)(T + (size_t)s0 * HID + 4 * t);
            uint2 v1 = *(const uint2*)(T + (size_t)s1 * HID + 4 * t);
            uint2 v2 = *(const uint2*)(T + (size_t)s2 * HID + 4 * t);
            uint2 v3 = *(const uint2*)(T + (size_t)s3 * HID + 4 * t);
            if (base + i     < dg) addv(acc, v0);
            if (base + i + 1 < dg) addv(acc, v1);
            if (base + i + 2 < dg) addv(acc, v2);
            if (base + i + 3 < dg) addv(acc, v3);
        }
        for (; i < lim; i++) {
            int s = __shfl(c, q * 16 + i, 64);
            uint2 v = *(const uint2*)(T + (size_t)s * HID + 4 * t);
            if (base + i < dg) addv(acc, v);
        }
    }

    float dv = dinv[d];
    float o[4] = {acc.x * dv, acc.y * dv, acc.z * dv, acc.w * dv};
    if (mode == 0) {
#pragma unroll
        for (int j = 0; j < 4; j++) {
            float v = o[j] + b[4 * t + j];
            float u2 = 0.7978845608028654f * (v + 0.044715f * v * v * v);
            o[j] = 0.5f * v * (1.0f + tanhf(u2)) * dv;   // pre-scale for next layer
        }
    }
    __half2 s0 = __floats2half2_rn(o[0], o[1]);
    __half2 s1 = __floats2half2_rn(o[2], o[3]);
    uint2 st; st.x = *(unsigned*)&s0; st.y = *(unsigned*)&s1;
    *(uint2*)(OUT + (size_t)d * HID + 4 * t) = st;
}

// ---------------- fused segmented mean-pool + final GEMM (batch is SORTED) ----------------

__global__ __launch_bounds__(256) void k_pool_out(const __half* __restrict__ A,
                                                  const int* __restrict__ batch,
                                                  const float* __restrict__ W3,
                                                  const float* __restrict__ b3,
                                                  float* __restrict__ out) {
    int g = blockIdx.x;
    int lo = 0, hi = N_NODES;
    while (lo < hi) { int m = (lo + hi) >> 1; if (batch[m] < g) lo = m + 1; else hi = m; }
    int lo2 = lo, hi2 = N_NODES;
    while (lo2 < hi2) { int m = (lo2 + hi2) >> 1; if (batch[m] < g + 1) lo2 = m + 1; else hi2 = m; }
    int start = lo, end = lo2;

    int lane = threadIdx.x & 63;
    int wave = threadIdx.x >> 6;
    float acc = 0.f;
    for (int n = start + wave; n < end; n += 4)
        acc += __half2float(A[(size_t)n * HID + lane]);

    __shared__ float part[4][HID];
    __shared__ float pooled[HID];
    part[wave][lane] = acc;
    __syncthreads();
    if (threadIdx.x < HID)
        pooled[threadIdx.x] = part[0][threadIdx.x] + part[1][threadIdx.x] +
                              part[2][threadIdx.x] + part[3][threadIdx.x];
    __syncthreads();

    if (threadIdx.x < OUT_DIM) {
        float cntf = (float)(end - start);
        float inv = 1.0f / fmaxf(cntf, 1.0f);
        float s = 0.f;
#pragma unroll
        for (int k = 0; k < HID; k++) s += pooled[k] * W3[k * OUT_DIM + threadIdx.x];
        out[g * OUT_DIM + threadIdx.x] = (s + cntf * b3[threadIdx.x]) * inv;
    }
}

// ---------------- launch ----------------

extern "C" void kernel_launch(void* const* d_in, const int* in_sizes, int n_in,
                              void* d_out, int out_size, void* d_ws, size_t ws_size,
                              hipStream_t stream) {
    const float* x     = (const float*)d_in[0];
    const int*   ei    = (const int*)d_in[1];
    const int*   batch = (const int*)d_in[2];
    const float* W1    = (const float*)d_in[4];
    const float* b1    = (const float*)d_in[5];
    const float* W2    = (const float*)d_in[6];
    const float* b2    = (const float*)d_in[7];
    const float* W3    = (const float*)d_in[8];
    const float* b3    = (const float*)d_in[9];
    float* out = (float*)d_out;

    const int* esrc = ei;
    const int* edst = ei + N_EDGES;

    // workspace layout
    int*    deg  = (int*)d_ws;                           // 50000 (zeroed; doubles as cursor)
    float*  dinv = (float*)(deg + N_NODES);              // 50000
    int*    col  = (int*)(dinv + N_NODES);               // 3.2M ints (12.8 MB)
    __half* t    = (__half*)(col + (size_t)N_NODES * MAX_DEG);   // 3.2M halves
    __half* p    = t + (size_t)N_NODES * HID;                    // 3.2M halves
    __half* Wt1  = p + (size_t)N_NODES * HID;                    // 8192 halves
    __half* Wt2  = Wt1 + IN_DIM * HID;                           // 4096 halves

    hipMemsetAsync(deg, 0, (size_t)N_NODES * 4, stream);

    const int CHUNKS = (N_EDGES + EPB - 1) / EPB;        // 196
    k_build<<<CHUNKS * PARTS, 256, 0, stream>>>(esrc, edst, deg, col);
    k_dinv<<<(N_NODES + 255) / 256, 256, 0, stream>>>(deg, dinv);
    k_pack<<<((IN_DIM / 8) * 64 + 255) / 256, 256, 0, stream>>>(W1, Wt1, IN_DIM);
    k_pack<<<((HID / 8) * 64 + 255) / 256, 256, 0, stream>>>(W2, Wt2, HID);

    const int GB = (N_NODES + 63) / 64;   // 782 MFMA blocks
    const int AB = N_NODES / 16;          // 3125 agg blocks (16 nodes each)

    // layer 1 (x-cvt + dinv pre-scale fused into MFMA A-load)
    k_mfma1<<<GB, 256, 0, stream>>>(x, dinv, Wt1, t);
    k_agg<<<AB, 256, 0, stream>>>(t, col, deg, dinv, b1, p, 0);
    // layer 2
    k_mfma2<<<GB, 256, 0, stream>>>(p, Wt2, t);
    k_agg<<<AB, 256, 0, stream>>>(t, col, deg, dinv, b2, p, 0);
    // layer 3 aggregate (width 64, pre-GEMM)
    k_agg<<<AB, 256, 0, stream>>>(p, col, deg, dinv, b3, t, 1);
    // fused mean-pool + 64->128 GEMM
    k_pool_out<<<N_GRAPHS, 256, 0, stream>>>(t, batch, W3, b3, out);
}

// Round 7
// 214.224 us; speedup vs baseline: 2.5679x; 1.0323x over previous
//
#include <hip/hip_runtime.h>
#include <hip/hip_fp16.h>
#include <math.h>

#define N_NODES   50000
#define N_EDGES   800000
#define IN_DIM    128
#define HID       64
#define OUT_DIM   128
#define N_GRAPHS  256
#define MAX_DEG   64      // ELL row stride; P(indeg>64) for Binomial(800k,1/50k) ~ 0
#define PARTS     8       // XCD count; blockIdx%8 -> XCD round-robin heuristic
#define PSIZE     (N_NODES / PARTS)
#define EPB       4096    // edges per build chunk
#define AGG_NPB   32      // nodes per agg block (4 waves x 8 octets)

typedef _Float16 half8 __attribute__((ext_vector_type(8)));
typedef float floatx4 __attribute__((ext_vector_type(4)));

// ---------------- preprocessing ----------------

// XCD-partitioned histogram + ELL fill (R5 write-churn fix)
__global__ __launch_bounds__(256) void k_build(const int* __restrict__ src,
                                               const int* __restrict__ dst,
                                               int* __restrict__ deg, int* __restrict__ col) {
    int p     = blockIdx.x & (PARTS - 1);
    int chunk = blockIdx.x >> 3;
    int base  = chunk * EPB;
    int lo = p * PSIZE, hi = lo + PSIZE;
#pragma unroll
    for (int j = 0; j < EPB / 256; j++) {
        int e = base + j * 256 + threadIdx.x;
        if (e < N_EDGES) {
            int d = dst[e];
            if (d >= lo && d < hi) {
                int pos = atomicAdd(&deg[d], 1);
                if (pos < MAX_DEG) col[d * MAX_DEG + pos] = src[e];
            }
        }
    }
}

// merged: dinv (blocks 0..195) + pack W1 (196..199) + pack W2 (200..201)
__global__ __launch_bounds__(256) void k_prep(const int* __restrict__ deg,
                                              float* __restrict__ dinv,
                                              const float* __restrict__ W1, __half* __restrict__ Wt1,
                                              const float* __restrict__ W2, __half* __restrict__ Wt2) {
    int blk = blockIdx.x;
    if (blk < 196) {
        int n = blk * 256 + threadIdx.x;
        if (n < N_NODES) dinv[n] = rsqrtf((float)(deg[n] + 1));  // +1 self-loop
    } else if (blk < 200) {
        int idx = (blk - 196) * 256 + threadIdx.x;   // 0..1023 = (128/8)*64
        int g = idx >> 6, n = idx & 63;
#pragma unroll
        for (int i = 0; i < 8; i++)
            Wt1[idx * 8 + i] = __float2half(W1[(8 * g + i) * 64 + n]);
    } else {
        int idx = (blk - 200) * 256 + threadIdx.x;   // 0..511 = (64/8)*64
        if (idx < 512) {
            int g = idx >> 6, n = idx & 63;
#pragma unroll
            for (int i = 0; i < 8; i++)
                Wt2[idx * 8 + i] = __float2half(W2[(8 * g + i) * 64 + n]);
        }
    }
}

// ---------------- MFMA GEMM layer 1: C = (dinv ⊙ x_fp32) @ W1, cvt fused ----------------

__global__ __launch_bounds__(256) void k_mfma1(const float* __restrict__ A,
                                               const float* __restrict__ dinv,
                                               const __half* __restrict__ Bp,
                                               __half* __restrict__ C) {
    constexpr int K = IN_DIM, S = K / 32;
    int wv   = threadIdx.x >> 6;
    int lane = threadIdx.x & 63;
    int quad = lane >> 4, l15 = lane & 15;
    int row0 = blockIdx.x * 64 + wv * 16;
    if (row0 >= N_NODES) return;   // 50000 % 16 == 0

    half8 bf[S][4];
#pragma unroll
    for (int s = 0; s < S; s++)
#pragma unroll
        for (int j = 0; j < 4; j++)
            bf[s][j] = *(const half8*)(Bp + ((size_t)((4 * s + quad) * 64 + 16 * j + l15)) * 8);

    floatx4 acc[4];
#pragma unroll
    for (int j = 0; j < 4; j++) acc[j] = 0.f;

    int arow = row0 + l15;
    float dv = dinv[arow];
#pragma unroll
    for (int s = 0; s < S; s++) {
        float4 xa = *(const float4*)(A + (size_t)arow * K + 32 * s + quad * 8);
        float4 xb = *(const float4*)(A + (size_t)arow * K + 32 * s + quad * 8 + 4);
        half8 af;
        af[0] = (_Float16)(xa.x * dv); af[1] = (_Float16)(xa.y * dv);
        af[2] = (_Float16)(xa.z * dv); af[3] = (_Float16)(xa.w * dv);
        af[4] = (_Float16)(xb.x * dv); af[5] = (_Float16)(xb.y * dv);
        af[6] = (_Float16)(xb.z * dv); af[7] = (_Float16)(xb.w * dv);
#pragma unroll
        for (int j = 0; j < 4; j++)
            acc[j] = __builtin_amdgcn_mfma_f32_16x16x32_f16(af, bf[s][j], acc[j], 0, 0, 0);
    }
#pragma unroll
    for (int j = 0; j < 4; j++)
#pragma unroll
        for (int r = 0; r < 4; r++)
            C[(size_t)(row0 + quad * 4 + r) * 64 + 16 * j + l15] = __float2half(acc[j][r]);
}

// ---------------- MFMA GEMM layer 2: fp16 A ----------------

__global__ __launch_bounds__(256) void k_mfma2(const __half* __restrict__ A,
                                               const __half* __restrict__ Bp,
                                               __half* __restrict__ C) {
    constexpr int K = HID, S = K / 32;
    int wv   = threadIdx.x >> 6;
    int lane = threadIdx.x & 63;
    int quad = lane >> 4, l15 = lane & 15;
    int row0 = blockIdx.x * 64 + wv * 16;
    if (row0 >= N_NODES) return;

    half8 bf[S][4];
#pragma unroll
    for (int s = 0; s < S; s++)
#pragma unroll
        for (int j = 0; j < 4; j++)
            bf[s][j] = *(const half8*)(Bp + ((size_t)((4 * s + quad) * 64 + 16 * j + l15)) * 8);

    floatx4 acc[4];
#pragma unroll
    for (int j = 0; j < 4; j++) acc[j] = 0.f;

    int arow = row0 + l15;
#pragma unroll
    for (int s = 0; s < S; s++) {
        half8 af = *(const half8*)(A + (size_t)arow * K + 32 * s + quad * 8);
#pragma unroll
        for (int j = 0; j < 4; j++)
            acc[j] = __builtin_amdgcn_mfma_f32_16x16x32_f16(af, bf[s][j], acc[j], 0, 0, 0);
    }
#pragma unroll
    for (int j = 0; j < 4; j++)
#pragma unroll
        for (int r = 0; r < 4; r++)
            C[(size_t)(row0 + quad * 4 + r) * 64 + 16 * j + l15] = __float2half(acc[j][r]);
}

// ---------------- aggregation v3: LDS-staged ELL, 8 nodes/wave, uint4 gathers ----------------
// mode 0: OUT = dinv * gelu_tanh( dinv*(Σ_in T[s] + T[d]) + b )   (pre-scaled for next layer)
// mode 1: OUT = dinv * (Σ_in T[s] + T[d])

__device__ __forceinline__ void add8(float* acc, uint4 v) {
    const __half2* h = (const __half2*)&v;
#pragma unroll
    for (int j = 0; j < 4; j++) {
        acc[2 * j]     += __low2float(h[j]);
        acc[2 * j + 1] += __high2float(h[j]);
    }
}

__global__ __launch_bounds__(256) void k_agg(const __half* __restrict__ T,
                                             const int* __restrict__ col,
                                             const int* __restrict__ indeg,
                                             const float* __restrict__ dinv,
                                             const float* __restrict__ b,
                                             __half* __restrict__ OUT, int mode) {
    __shared__ int cols[AGG_NPB][MAX_DEG + 1];   // +1 pad: octets land in distinct banks
    int base = blockIdx.x * AGG_NPB;

    for (int idx = threadIdx.x; idx < AGG_NPB * MAX_DEG; idx += 256) {
        int r = idx >> 6, j = idx & 63;
        int g = base + r;
        if (g < N_NODES) cols[r][j] = col[g * MAX_DEG + j];
    }
    __syncthreads();

    int lane = threadIdx.x & 63;
    int wv   = threadIdx.x >> 6;
    int q = lane >> 3, t = lane & 7;     // octet = node, t = 16-byte chunk
    int local = wv * 8 + q;
    int d = base + local;
    if (d >= N_NODES) return;            // tail block: whole octets drop out

    int dg = indeg[d]; if (dg > MAX_DEG) dg = MAX_DEG;

    float acc[8];
#pragma unroll
    for (int j = 0; j < 8; j++) acc[j] = 0.f;
    add8(acc, *(const uint4*)(T + (size_t)d * HID + t * 8));   // self term

    const int* cl = cols[local];
    int i = 0;
    for (; i + 4 <= dg; i += 4) {
        int s0 = cl[i], s1 = cl[i + 1], s2 = cl[i + 2], s3 = cl[i + 3];
        uint4 v0 = *(const uint4*)(T + (size_t)s0 * HID + t * 8);
        uint4 v1 = *(const uint4*)(T + (size_t)s1 * HID + t * 8);
        uint4 v2 = *(const uint4*)(T + (size_t)s2 * HID + t * 8);
        uint4 v3 = *(const uint4*)(T + (size_t)s3 * HID + t * 8);
        add8(acc, v0); add8(acc, v1); add8(acc, v2); add8(acc, v3);
    }
    for (; i < dg; i++) {
        int s = cl[i];
        add8(acc, *(const uint4*)(T + (size_t)s * HID + t * 8));
    }

    float dv = dinv[d];
    float o[8];
#pragma unroll
    for (int j = 0; j < 8; j++) o[j] = acc[j] * dv;
    if (mode == 0) {
#pragma unroll
        for (int j = 0; j < 8; j++) {
            float v = o[j] + b[t * 8 + j];
            float u2 = 0.7978845608028654f * (v + 0.044715f * v * v * v);
            o[j] = 0.5f * v * (1.0f + tanhf(u2)) * dv;   // pre-scale for next layer
        }
    }
    __half2 hh[4];
#pragma unroll
    for (int j = 0; j < 4; j++) hh[j] = __floats2half2_rn(o[2 * j], o[2 * j + 1]);
    *(uint4*)(OUT + (size_t)d * HID + t * 8) = *(uint4*)hh;
}

// ---------------- fused segmented mean-pool + final GEMM (batch is SORTED) ----------------

__global__ __launch_bounds__(256) void k_pool_out(const __half* __restrict__ A,
                                                  const int* __restrict__ batch,
                                                  const float* __restrict__ W3,
                                                  const float* __restrict__ b3,
                                                  float* __restrict__ out) {
    int g = blockIdx.x;
    int lo = 0, hi = N_NODES;
    while (lo < hi) { int m = (lo + hi) >> 1; if (batch[m] < g) lo = m + 1; else hi = m; }
    int lo2 = lo, hi2 = N_NODES;
    while (lo2 < hi2) { int m = (lo2 + hi2) >> 1; if (batch[m] < g + 1) lo2 = m + 1; else hi2 = m; }
    int start = lo, end = lo2;

    int lane = threadIdx.x & 63;
    int wave = threadIdx.x >> 6;
    float acc = 0.f;
    for (int n = start + wave; n < end; n += 4)
        acc += __half2float(A[(size_t)n * HID + lane]);

    __shared__ float part[4][HID];
    __shared__ float pooled[HID];
    part[wave][lane] = acc;
    __syncthreads();
    if (threadIdx.x < HID)
        pooled[threadIdx.x] = part[0][threadIdx.x] + part[1][threadIdx.x] +
                              part[2][threadIdx.x] + part[3][threadIdx.x];
    __syncthreads();

    if (threadIdx.x < OUT_DIM) {
        float cntf = (float)(end - start);
        float inv = 1.0f / fmaxf(cntf, 1.0f);
        float s = 0.f;
#pragma unroll
        for (int k = 0; k < HID; k++) s += pooled[k] * W3[k * OUT_DIM + threadIdx.x];
        out[g * OUT_DIM + threadIdx.x] = (s + cntf * b3[threadIdx.x]) * inv;
    }
}

// ---------------- launch ----------------

extern "C" void kernel_launch(void* const* d_in, const int* in_sizes, int n_in,
                              void* d_out, int out_size, void* d_ws, size_t ws_size,
                              hipStream_t stream) {
    const float* x     = (const float*)d_in[0];
    const int*   ei    = (const int*)d_in[1];
    const int*   batch = (const int*)d_in[2];
    const float* W1    = (const float*)d_in[4];
    const float* b1    = (const float*)d_in[5];
    const float* W2    = (const float*)d_in[6];
    const float* b2    = (const float*)d_in[7];
    const float* W3    = (const float*)d_in[8];
    const float* b3    = (const float*)d_in[9];
    float* out = (float*)d_out;

    const int* esrc = ei;
    const int* edst = ei + N_EDGES;

    // workspace layout
    int*    deg  = (int*)d_ws;                           // 50000 (zeroed; doubles as cursor)
    float*  dinv = (float*)(deg + N_NODES);              // 50000
    int*    col  = (int*)(dinv + N_NODES);               // 3.2M ints (12.8 MB)
    __half* t    = (__half*)(col + (size_t)N_NODES * MAX_DEG);   // 3.2M halves
    __half* p    = t + (size_t)N_NODES * HID;                    // 3.2M halves
    __half* Wt1  = p + (size_t)N_NODES * HID;                    // 8192 halves
    __half* Wt2  = Wt1 + IN_DIM * HID;                           // 4096 halves

    hipMemsetAsync(deg, 0, (size_t)N_NODES * 4, stream);

    const int CHUNKS = (N_EDGES + EPB - 1) / EPB;        // 196
    k_build<<<CHUNKS * PARTS, 256, 0, stream>>>(esrc, edst, deg, col);
    k_prep<<<202, 256, 0, stream>>>(deg, dinv, W1, Wt1, W2, Wt2);

    const int GB = (N_NODES + 63) / 64;        // 782 MFMA blocks
    const int AB = (N_NODES + AGG_NPB - 1) / AGG_NPB;   // 1563 agg blocks

    // layer 1 (x-cvt + dinv pre-scale fused into MFMA A-load)
    k_mfma1<<<GB, 256, 0, stream>>>(x, dinv, Wt1, t);
    k_agg<<<AB, 256, 0, stream>>>(t, col, deg, dinv, b1, p, 0);
    // layer 2
    k_mfma2<<<GB, 256, 0, stream>>>(p, Wt2, t);
    k_agg<<<AB, 256, 0, stream>>>(t, col, deg, dinv, b2, p, 0);
    // layer 3 aggregate (width 64, pre-GEMM)
    k_agg<<<AB, 256, 0, stream>>>(p, col, deg, dinv, b3, t, 1);
    // fused mean-pool + 64->128 GEMM
    k_pool_out<<<N_GRAPHS, 256, 0, stream>>>(t, batch, W3, b3, out);
}